// Round 11
// baseline (114.036 us; speedup 1.0000x reference)
//
#include <hip/hip_runtime.h>

// VQ linear: out[b][o] = sum_k x[b][k] * dq[o][k]
// dq[o][k]: word = qweight[o][k/16]; nibble = (k/2)%8; idx = (word>>(4*nibble))&15;
//           dq[o][k] = lut[idx][k%2]
// Device dtypes (harness promotes reference f16 -> f32):
//   x (16,8192) f32, qweight (8192,512) i32, lut (16,2) f32, out (16,8192) f32.
// Values are exactly f16-representable -> lossless f32->f16, f16 MFMA, f32 accum.
//
// ROUND 11 (= round 10 resubmit after infra failure): round-8 structure
// (pairlut b64 lookups). Gemm launched 3x (idempotent) for differential
// timing: T_gemm = (dur_us - 81.1)/2.

typedef _Float16 half8 __attribute__((ext_vector_type(8)));
typedef _Float16 half4_t __attribute__((ext_vector_type(4)));
typedef float float4_t __attribute__((ext_vector_type(4)));
typedef unsigned int uint4_t __attribute__((ext_vector_type(4)));

#define O_FEAT 8192
#define I_FEAT 8192
#define WAVES 16
#define K_PER_WAVE (I_FEAT / WAVES)   // 512 halves = 64 u16 per row per wave
#define NJ (K_PER_WAVE / 32)          // 16 MFMA K-steps per wave
#define TILES 2                       // 32 outputs per block

// ---- pre-kernel: convert x f32 -> f16 into workspace (lossless) ----
__global__ void cvt_x_kernel(const float* __restrict__ x, _Float16* __restrict__ xf) {
    int i = (blockIdx.x * 256 + threadIdx.x) * 8;
    float4_t f0 = *(const float4_t*)(x + i);
    float4_t f1 = *(const float4_t*)(x + i + 4);
    half8 h = { (_Float16)f0[0], (_Float16)f0[1], (_Float16)f0[2], (_Float16)f0[3],
                (_Float16)f1[0], (_Float16)f1[1], (_Float16)f1[2], (_Float16)f1[3] };
    *(half8*)(xf + i) = h;
}

template <bool XF16>
__launch_bounds__(1024, 4)
__global__ void vq_gemm_kernel(const void* __restrict__ xsrc,
                               const unsigned char* __restrict__ qwb,  // qweight bytes
                               const float* __restrict__ lutf,         // lut (16,2) f32
                               float* __restrict__ out) {
    // Byte-pair dequant table: byte v -> 4 f16 {lut[v&15].xy, lut[v>>4].xy}
    __shared__ half4_t pairlut[256];
    __shared__ float4_t red[WAVES][TILES * 64];

    const int tid = threadIdx.x;
    if (tid < 256) {
        half4_t v;
        v[0] = (_Float16)lutf[(tid & 15) * 2 + 0];
        v[1] = (_Float16)lutf[(tid & 15) * 2 + 1];
        v[2] = (_Float16)lutf[(tid >> 4) * 2 + 0];
        v[3] = (_Float16)lutf[(tid >> 4) * 2 + 1];
        pairlut[tid] = v;
    }

    const int wave = tid >> 6;
    const int lane = tid & 63;
    const int ln15 = lane & 15;   // A: batch row; B: output col within tile
    const int g    = lane >> 4;   // k-group 0..3

    const int obase = blockIdx.x * (TILES * 16);

    // qweight row = 2048 B; wave slice = 128 B; lane chunk = 32 B (contiguous)
    const unsigned char* qp0 = qwb + (size_t)(obase + ln15) * 2048 + wave * 128 + g * 32;
    const unsigned char* qp1 = qp0 + 16 * 2048;   // second 16-output tile

    uint4_t qa0 = *(const uint4_t*)(qp0);        // u16 idx 16g+0..7  (j=0..7)
    uint4_t qb0 = *(const uint4_t*)(qp0 + 16);   // u16 idx 16g+8..15 (j=8..15)
    uint4_t qa1 = *(const uint4_t*)(qp1);
    uint4_t qb1 = *(const uint4_t*)(qp1 + 16);

    const int xoff = ln15 * I_FEAT + wave * K_PER_WAVE + 128 * g;

    __syncthreads();   // pairlut ready

    float4_t acc0 = {0.f, 0.f, 0.f, 0.f};
    float4_t acc1 = {0.f, 0.f, 0.f, 0.f};

#pragma unroll
    for (int j = 0; j < NJ; ++j) {
        half8 a;
        if constexpr (XF16) {
            a = *(const half8*)((const _Float16*)xsrc + xoff + 8 * j);
        } else {
            const float* xp = (const float*)xsrc + xoff + 8 * j;
            float4_t f0 = *(const float4_t*)xp;
            float4_t f1 = *(const float4_t*)(xp + 4);
            a = (half8){ (_Float16)f0[0], (_Float16)f0[1], (_Float16)f0[2], (_Float16)f0[3],
                         (_Float16)f1[0], (_Float16)f1[1], (_Float16)f1[2], (_Float16)f1[3] };
        }
        // u16 (16g + j): j<8 in qa*, j>=8 in qb*; odd j = high half of the u32.
        unsigned int w0 = (j < 8) ? qa0[(j >> 1) & 3] : qb0[(j >> 1) & 3];
        unsigned int w1 = (j < 8) ? qa1[(j >> 1) & 3] : qb1[(j >> 1) & 3];
        if (j & 1) { w0 >>= 16; w1 >>= 16; }
        half4_t p00 = pairlut[w0 & 0xFF];          // k-offsets 0..3
        half4_t p01 = pairlut[(w0 >> 8) & 0xFF];   // k-offsets 4..7
        half4_t p10 = pairlut[w1 & 0xFF];
        half4_t p11 = pairlut[(w1 >> 8) & 0xFF];
        half8 b0 = __builtin_shufflevector(p00, p01, 0, 1, 2, 3, 4, 5, 6, 7);
        half8 b1 = __builtin_shufflevector(p10, p11, 0, 1, 2, 3, 4, 5, 6, 7);
        acc0 = __builtin_amdgcn_mfma_f32_16x16x32_f16(a, b0, acc0, 0, 0, 0);
        acc1 = __builtin_amdgcn_mfma_f32_16x16x32_f16(a, b1, acc1, 0, 0, 0);
    }

    // Cross-wave K reduction via LDS (b128 writes, conflict-free).
    red[wave][lane] = acc0;
    red[wave][64 + lane] = acc1;
    __syncthreads();

    if (tid < 512) {
        const float* rf = (const float*)red;
        float s = 0.f;
#pragma unroll
        for (int w = 0; w < WAVES; ++w)
            s += rf[w * (TILES * 64 * 4) + tid];
        // tid -> (tile, lane, reg): D col n = lane&15, row m = (lane>>4)*4 + reg
        const int t2 = tid >> 8;
        const int l  = (tid >> 2) & 63;
        const int r  = tid & 3;
        const int m  = (l >> 4) * 4 + r;
        const int n  = l & 15;
        out[m * O_FEAT + obase + t2 * 16 + n] = s;
    }
}

extern "C" void kernel_launch(void* const* d_in, const int* in_sizes, int n_in,
                              void* d_out, int out_size, void* d_ws, size_t ws_size,
                              hipStream_t stream) {
    const float* x = (const float*)d_in[0];
    const unsigned char* qwb = (const unsigned char*)d_in[1];
    const float* lutf = (const float*)d_in[2];
    float* out = (float*)d_out;

    dim3 grid(O_FEAT / (TILES * 16));   // 256 blocks of 32 outputs (1 per CU)
    dim3 block(1024);                   // 16 waves: 16-way K split

    if (ws_size >= (size_t)(16 * I_FEAT * 2)) {
        cvt_x_kernel<<<dim3(16 * I_FEAT / (256 * 8)), dim3(256), 0, stream>>>(x, (_Float16*)d_ws);
        // Launched 3x for differential timing (idempotent: pure function of
        // inputs, all three write identical values). Same work every call.
        vq_gemm_kernel<true><<<grid, block, 0, stream>>>(d_ws, qwb, lutf, out);
        vq_gemm_kernel<true><<<grid, block, 0, stream>>>(d_ws, qwb, lutf, out);
        vq_gemm_kernel<true><<<grid, block, 0, stream>>>(d_ws, qwb, lutf, out);
    } else {
        vq_gemm_kernel<false><<<grid, block, 0, stream>>>(x, qwb, lutf, out);
        vq_gemm_kernel<false><<<grid, block, 0, stream>>>(x, qwb, lutf, out);
        vq_gemm_kernel<false><<<grid, block, 0, stream>>>(x, qwb, lutf, out);
    }
}

// Round 16
// 74.606 us; speedup vs baseline: 1.5285x; 1.5285x over previous
//
#include <hip/hip_runtime.h>

// VQ linear: out[b][o] = sum_k x[b][k] * dq[o][k]
// dq[o][k]: word = qweight[o][k/16]; nibble = (k/2)%8; idx = (word>>(4*nibble))&15;
//           dq[o][k] = lut[idx][k%2]
// Device dtypes (harness promotes reference f16 -> f32):
//   x (16,8192) f32, qweight (8192,512) i32, lut (16,2) f32, out (16,8192) f32.
// Values are exactly f16-representable -> lossless f32->f16, f16 MFMA, f32 accum.
//
// ROUND 16 (resubmit of r12-r15 after infra timeouts): fragment-ordered x.
// r11 differential timing: T_gemm ~= 15-16 us; ~9 modeled -> missing term =
// scattered A-fragment loads. cvt_x emits x in per-(wave,j,lane) fragment
// order so each (wave,j) A-load is one contiguous 1KB wave access, identical
// across blocks (L2 broadcast). Single gemm launch.

typedef _Float16 half8 __attribute__((ext_vector_type(8)));
typedef _Float16 half4_t __attribute__((ext_vector_type(4)));
typedef float float4_t __attribute__((ext_vector_type(4)));
typedef unsigned int uint4_t __attribute__((ext_vector_type(4)));

#define O_FEAT 8192
#define I_FEAT 8192
#define WAVES 16
#define K_PER_WAVE (I_FEAT / WAVES)   // 512 halves = 64 u16 per row per wave
#define NJ (K_PER_WAVE / 32)          // 16 MFMA K-steps per wave
#define TILES 2                       // 32 outputs per block

// ---- pre-kernel: x f32 -> f16, written in per-(wave,j,lane) fragment order ----
// cell c = (w*16 + j)*64 + lane; lane = g*16 + ln15; the 8 halves are
// x[row = ln15][col = w*512 + g*128 + j*8 .. +8)  (matches gemm's K-mapping).
__global__ void cvt_x_frag_kernel(const float* __restrict__ x, _Float16* __restrict__ xf) {
    const int c = blockIdx.x * 256 + threadIdx.x;   // 16384 cells
    const int w    = c >> 10;
    const int j    = (c >> 6) & 15;
    const int lane = c & 63;
    const int row  = lane & 15;
    const int col  = w * K_PER_WAVE + (lane >> 4) * 128 + j * 8;
    const float* xp = x + row * I_FEAT + col;
    float4_t f0 = *(const float4_t*)xp;
    float4_t f1 = *(const float4_t*)(xp + 4);
    half8 h = { (_Float16)f0[0], (_Float16)f0[1], (_Float16)f0[2], (_Float16)f0[3],
                (_Float16)f1[0], (_Float16)f1[1], (_Float16)f1[2], (_Float16)f1[3] };
    *(half8*)(xf + (size_t)c * 8) = h;
}

template <bool XF16>
__launch_bounds__(1024, 4)
__global__ void vq_gemm_kernel(const void* __restrict__ xsrc,
                               const unsigned char* __restrict__ qwb,  // qweight bytes
                               const float* __restrict__ lutf,         // lut (16,2) f32
                               float* __restrict__ out) {
    // Byte-pair dequant table: byte v -> 4 f16 {lut[v&15].xy, lut[v>>4].xy}
    __shared__ half4_t pairlut[256];
    __shared__ float4_t red[WAVES][TILES * 64];

    const int tid = threadIdx.x;
    if (tid < 256) {
        half4_t v;
        v[0] = (_Float16)lutf[(tid & 15) * 2 + 0];
        v[1] = (_Float16)lutf[(tid & 15) * 2 + 1];
        v[2] = (_Float16)lutf[(tid >> 4) * 2 + 0];
        v[3] = (_Float16)lutf[(tid >> 4) * 2 + 1];
        pairlut[tid] = v;
    }

    const int wave = tid >> 6;
    const int lane = tid & 63;
    const int ln15 = lane & 15;   // A: batch row; B: output col within tile
    const int g    = lane >> 4;   // k-group 0..3

    const int obase = blockIdx.x * (TILES * 16);

    // qweight row = 2048 B; wave slice = 128 B; lane chunk = 32 B (contiguous)
    const unsigned char* qp0 = qwb + (size_t)(obase + ln15) * 2048 + wave * 128 + g * 32;
    const unsigned char* qp1 = qp0 + 16 * 2048;   // second 16-output tile

    uint4_t qa0 = *(const uint4_t*)(qp0);        // u16 idx 16g+0..7  (j=0..7)
    uint4_t qb0 = *(const uint4_t*)(qp0 + 16);   // u16 idx 16g+8..15 (j=8..15)
    uint4_t qa1 = *(const uint4_t*)(qp1);
    uint4_t qb1 = *(const uint4_t*)(qp1 + 16);

    // Fragment-ordered x: wave base + lane*8; step 512 halves per j.
    const _Float16* xfrag = (const _Float16*)xsrc + (size_t)wave * (NJ * 64 * 8) + lane * 8;
    // Fallback (non-XF16): original row-major offsets.
    const int xoff = ln15 * I_FEAT + wave * K_PER_WAVE + 128 * g;

    __syncthreads();   // pairlut ready

    float4_t acc0 = {0.f, 0.f, 0.f, 0.f};
    float4_t acc1 = {0.f, 0.f, 0.f, 0.f};

#pragma unroll
    for (int j = 0; j < NJ; ++j) {
        half8 a;
        if constexpr (XF16) {
            a = *(const half8*)(xfrag + j * (64 * 8));   // contiguous 1KB per wave
        } else {
            const float* xp = (const float*)xsrc + xoff + 8 * j;
            float4_t f0 = *(const float4_t*)xp;
            float4_t f1 = *(const float4_t*)(xp + 4);
            a = (half8){ (_Float16)f0[0], (_Float16)f0[1], (_Float16)f0[2], (_Float16)f0[3],
                         (_Float16)f1[0], (_Float16)f1[1], (_Float16)f1[2], (_Float16)f1[3] };
        }
        // u16 (16g + j): j<8 in qa*, j>=8 in qb*; odd j = high half of the u32.
        unsigned int w0 = (j < 8) ? qa0[(j >> 1) & 3] : qb0[(j >> 1) & 3];
        unsigned int w1 = (j < 8) ? qa1[(j >> 1) & 3] : qb1[(j >> 1) & 3];
        if (j & 1) { w0 >>= 16; w1 >>= 16; }
        half4_t p00 = pairlut[w0 & 0xFF];          // k-offsets 0..3
        half4_t p01 = pairlut[(w0 >> 8) & 0xFF];   // k-offsets 4..7
        half4_t p10 = pairlut[w1 & 0xFF];
        half4_t p11 = pairlut[(w1 >> 8) & 0xFF];
        half8 b0 = __builtin_shufflevector(p00, p01, 0, 1, 2, 3, 4, 5, 6, 7);
        half8 b1 = __builtin_shufflevector(p10, p11, 0, 1, 2, 3, 4, 5, 6, 7);
        acc0 = __builtin_amdgcn_mfma_f32_16x16x32_f16(a, b0, acc0, 0, 0, 0);
        acc1 = __builtin_amdgcn_mfma_f32_16x16x32_f16(a, b1, acc1, 0, 0, 0);
    }

    // Cross-wave K reduction via LDS (b128 writes, conflict-free).
    red[wave][lane] = acc0;
    red[wave][64 + lane] = acc1;
    __syncthreads();

    if (tid < 512) {
        const float* rf = (const float*)red;
        float s = 0.f;
#pragma unroll
        for (int w = 0; w < WAVES; ++w)
            s += rf[w * (TILES * 64 * 4) + tid];
        // tid -> (tile, lane, reg): D col n = lane&15, row m = (lane>>4)*4 + reg
        const int t2 = tid >> 8;
        const int l  = (tid >> 2) & 63;
        const int r  = tid & 3;
        const int m  = (l >> 4) * 4 + r;
        const int n  = l & 15;
        out[m * O_FEAT + obase + t2 * 16 + n] = s;
    }
}

extern "C" void kernel_launch(void* const* d_in, const int* in_sizes, int n_in,
                              void* d_out, int out_size, void* d_ws, size_t ws_size,
                              hipStream_t stream) {
    const float* x = (const float*)d_in[0];
    const unsigned char* qwb = (const unsigned char*)d_in[1];
    const float* lutf = (const float*)d_in[2];
    float* out = (float*)d_out;

    dim3 grid(O_FEAT / (TILES * 16));   // 256 blocks of 32 outputs (1 per CU)
    dim3 block(1024);                   // 16 waves: 16-way K split

    if (ws_size >= (size_t)(16 * I_FEAT * 2)) {
        cvt_x_frag_kernel<<<dim3(16384 / 256), dim3(256), 0, stream>>>(x, (_Float16*)d_ws);
        vq_gemm_kernel<true><<<grid, block, 0, stream>>>(d_ws, qwb, lutf, out);
    } else {
        vq_gemm_kernel<false><<<grid, block, 0, stream>>>(x, qwb, lutf, out);
    }
}

// Round 19
// 74.591 us; speedup vs baseline: 1.5288x; 1.0002x over previous
//
#include <hip/hip_runtime.h>

// VQ linear: out[b][o] = sum_k x[b][k] * dq[o][k]
// dq[o][k]: word = qweight[o][k/16]; nibble = (k/2)%8; idx = (word>>(4*nibble))&15;
//           dq[o][k] = lut[idx][k%2]
// Device dtypes (harness promotes reference f16 -> f32):
//   x (16,8192) f32, qweight (8192,512) i32, lut (16,2) f32, out (16,8192) f32.
// Values are exactly f16-representable -> lossless f32->f16, f16 MFMA, f32 accum.
//
// ROUND 19 (resubmit of r17/r18 after infra timeouts): bpermute dequant.
// r16 confirmed frag-x (+6.5 us). Remaining gemm cost ~9 us ~= LDS pipe:
// 1024 random-index ds_read_b64/CU at ~25-30cy (bank bins = 2*(byte&15),
// 64 lanes over 16 bins -> ~8-way). Replace table reads with ds_bpermute_b32
// (crossbar, conflict-free for ANY indices): lane i holds lut[i&15] packed
// 2xf16 in a register; nibble lookup = bpermute(idx<<2). 4 bpermutes/tile-j
// vs 2 conflicted b64. Bit-identical values; pairlut + leading barrier gone.

typedef _Float16 half8 __attribute__((ext_vector_type(8)));
typedef float float4_t __attribute__((ext_vector_type(4)));
typedef unsigned int uint4_t __attribute__((ext_vector_type(4)));

#define O_FEAT 8192
#define I_FEAT 8192
#define WAVES 16
#define K_PER_WAVE (I_FEAT / WAVES)   // 512 halves = 64 u16 per row per wave
#define NJ (K_PER_WAVE / 32)          // 16 MFMA K-steps per wave
#define TILES 2                       // 32 outputs per block

// ---- pre-kernel: x f32 -> f16, written in per-(wave,j,lane) fragment order ----
__global__ void cvt_x_frag_kernel(const float* __restrict__ x, _Float16* __restrict__ xf) {
    const int c = blockIdx.x * 256 + threadIdx.x;   // 16384 cells
    const int w    = c >> 10;
    const int j    = (c >> 6) & 15;
    const int lane = c & 63;
    const int row  = lane & 15;
    const int col  = w * K_PER_WAVE + (lane >> 4) * 128 + j * 8;
    const float* xp = x + row * I_FEAT + col;
    float4_t f0 = *(const float4_t*)xp;
    float4_t f1 = *(const float4_t*)(xp + 4);
    half8 h = { (_Float16)f0[0], (_Float16)f0[1], (_Float16)f0[2], (_Float16)f0[3],
                (_Float16)f1[0], (_Float16)f1[1], (_Float16)f1[2], (_Float16)f1[3] };
    *(half8*)(xf + (size_t)c * 8) = h;
}

__device__ __forceinline__ unsigned int bperm_lut(unsigned int idx4, int lutreg) {
    return (unsigned int)__builtin_amdgcn_ds_bpermute((int)idx4, lutreg);
}

template <bool XF16>
__launch_bounds__(1024, 4)
__global__ void vq_gemm_kernel(const void* __restrict__ xsrc,
                               const unsigned char* __restrict__ qwb,  // qweight bytes
                               const float* __restrict__ lutf,         // lut (16,2) f32
                               float* __restrict__ out) {
    __shared__ float4_t red[WAVES][TILES * 64];

    const int tid = threadIdx.x;
    const int wave = tid >> 6;
    const int lane = tid & 63;
    const int ln15 = lane & 15;   // A: batch row; B: output col within tile
    const int g    = lane >> 4;   // k-group 0..3

    // Lane-resident LUT: lane i holds lut[i&15] as packed 2xf16 (lo = [0]).
    int lutreg;
    {
        const int e = ln15;
        _Float16 lo = (_Float16)lutf[e * 2 + 0];
        _Float16 hi = (_Float16)lutf[e * 2 + 1];
        unsigned int u = ((unsigned int)__builtin_bit_cast(unsigned short, hi) << 16)
                       |  (unsigned int)__builtin_bit_cast(unsigned short, lo);
        lutreg = (int)u;
    }

    const int obase = blockIdx.x * (TILES * 16);

    // qweight row = 2048 B; wave slice = 128 B; lane chunk = 32 B (contiguous)
    const unsigned char* qp0 = qwb + (size_t)(obase + ln15) * 2048 + wave * 128 + g * 32;
    const unsigned char* qp1 = qp0 + 16 * 2048;   // second 16-output tile

    uint4_t qa0 = *(const uint4_t*)(qp0);        // u16 idx 16g+0..7  (j=0..7)
    uint4_t qb0 = *(const uint4_t*)(qp0 + 16);   // u16 idx 16g+8..15 (j=8..15)
    uint4_t qa1 = *(const uint4_t*)(qp1);
    uint4_t qb1 = *(const uint4_t*)(qp1 + 16);

    // Fragment-ordered x: wave base + lane*8; step 512 halves per j.
    const _Float16* xfrag = (const _Float16*)xsrc + (size_t)wave * (NJ * 64 * 8) + lane * 8;
    // Fallback (non-XF16): original row-major offsets.
    const int xoff = ln15 * I_FEAT + wave * K_PER_WAVE + 128 * g;

    float4_t acc0 = {0.f, 0.f, 0.f, 0.f};
    float4_t acc1 = {0.f, 0.f, 0.f, 0.f};

#pragma unroll
    for (int j = 0; j < NJ; ++j) {
        half8 a;
        if constexpr (XF16) {
            a = *(const half8*)(xfrag + j * (64 * 8));   // contiguous 1KB per wave
        } else {
            const float* xp = (const float*)xsrc + xoff + 8 * j;
            float4_t f0 = *(const float4_t*)xp;
            float4_t f1 = *(const float4_t*)(xp + 4);
            a = (half8){ (_Float16)f0[0], (_Float16)f0[1], (_Float16)f0[2], (_Float16)f0[3],
                         (_Float16)f1[0], (_Float16)f1[1], (_Float16)f1[2], (_Float16)f1[3] };
        }
        // u16 (16g + j): j<8 in qa*, j>=8 in qb*; odd j = high half of the u32.
        unsigned int w0 = (j < 8) ? qa0[(j >> 1) & 3] : qb0[(j >> 1) & 3];
        unsigned int w1 = (j < 8) ? qa1[(j >> 1) & 3] : qb1[(j >> 1) & 3];
        if (j & 1) { w0 >>= 16; w1 >>= 16; }
        // 4 nibbles -> 4 conflict-free crossbar lookups, index = nibble*4.
        uint4_t u0, u1;
        u0[0] = bperm_lut((w0 << 2) & 60, lutreg);
        u0[1] = bperm_lut((w0 >> 2) & 60, lutreg);
        u0[2] = bperm_lut((w0 >> 6) & 60, lutreg);
        u0[3] = bperm_lut((w0 >> 10) & 60, lutreg);
        u1[0] = bperm_lut((w1 << 2) & 60, lutreg);
        u1[1] = bperm_lut((w1 >> 2) & 60, lutreg);
        u1[2] = bperm_lut((w1 >> 6) & 60, lutreg);
        u1[3] = bperm_lut((w1 >> 10) & 60, lutreg);
        half8 b0 = __builtin_bit_cast(half8, u0);
        half8 b1 = __builtin_bit_cast(half8, u1);
        acc0 = __builtin_amdgcn_mfma_f32_16x16x32_f16(a, b0, acc0, 0, 0, 0);
        acc1 = __builtin_amdgcn_mfma_f32_16x16x32_f16(a, b1, acc1, 0, 0, 0);
    }

    // Cross-wave K reduction via LDS (b128 writes, conflict-free).
    red[wave][lane] = acc0;
    red[wave][64 + lane] = acc1;
    __syncthreads();

    if (tid < 512) {
        const float* rf = (const float*)red;
        float s = 0.f;
#pragma unroll
        for (int w = 0; w < WAVES; ++w)
            s += rf[w * (TILES * 64 * 4) + tid];
        // tid -> (tile, lane, reg): D col n = lane&15, row m = (lane>>4)*4 + reg
        const int t2 = tid >> 8;
        const int l  = (tid >> 2) & 63;
        const int r  = tid & 3;
        const int m  = (l >> 4) * 4 + r;
        const int n  = l & 15;
        out[m * O_FEAT + obase + t2 * 16 + n] = s;
    }
}

extern "C" void kernel_launch(void* const* d_in, const int* in_sizes, int n_in,
                              void* d_out, int out_size, void* d_ws, size_t ws_size,
                              hipStream_t stream) {
    const float* x = (const float*)d_in[0];
    const unsigned char* qwb = (const unsigned char*)d_in[1];
    const float* lutf = (const float*)d_in[2];
    float* out = (float*)d_out;

    dim3 grid(O_FEAT / (TILES * 16));   // 256 blocks of 32 outputs (1 per CU)
    dim3 block(1024);                   // 16 waves: 16-way K split

    if (ws_size >= (size_t)(16 * I_FEAT * 2)) {
        cvt_x_frag_kernel<<<dim3(16384 / 256), dim3(256), 0, stream>>>(x, (_Float16*)d_ws);
        vq_gemm_kernel<true><<<grid, block, 0, stream>>>(d_ws, qwb, lutf, out);
    } else {
        vq_gemm_kernel<false><<<grid, block, 0, stream>>>(x, qwb, lutf, out);
    }
}